// Round 6
// baseline (129.061 us; speedup 1.0000x reference)
//
#include <hip/hip_runtime.h>
#include <stdint.h>

// Problem: LTCCell  B=256, I=512, H=512. ALL tensors float32, output float32.
// R4: TB=8 + r[8] ILP, 4 w/SIMD -> 48us, VALUBusy 58%, occ 29%.
// R5: 8 w/SIMD (side folded into split) -> 46.5us, VALUBusy STILL 58%, occ 51%.
//     TLP doubling changed nothing -> correlated all-wave vmcnt stalls on
//     param loads (every XCD touches all 8.4MB of params > 4MiB L2; waves
//     phase-locked out of the staging barrier).
// R6: (a) XCD-aware sigma swizzle: XCD = bi%8 (round-robin dispatch), give
//     each XCD only 4 sigma-chunks = 1MB params -> L2-resident.
//     (b) explicit distance-2 register prefetch of the 4 param streams.
constexpr int NB = 256;
constexpr int NI = 512;
constexpr int NH = 512;

constexpr int TB    = 8;    // batches register-blocked per lane
constexpr int NT    = 32;   // batch tiles: 256/8
constexpr int CHUNK = 32;   // reduction rows per block
constexpr int NSPL  = 32;   // splits: 16 sensory chunks + 16 inter chunks
constexpr int HBLK  = 256;  // h columns per block (== blockDim.x)

__device__ __forceinline__ float fast_exp2(float x) {
#if __has_builtin(__builtin_amdgcn_exp2f)
    return __builtin_amdgcn_exp2f(x);
#else
    return exp2f(x);
#endif
}
__device__ __forceinline__ float fast_rcp(float x) {
#if __has_builtin(__builtin_amdgcn_rcpf)
    return __builtin_amdgcn_rcpf(x);
#else
    return 1.0f / x;
#endif
}

// Each block = (split sigma, batch tile, h half). 2048 blocks x 256 thr =
// 8 blocks/CU = 8 waves/SIMD. Lane <-> h column, 8 batches register-blocked
// per lane (r[8] ILP array). Partials combined via f32 atomics.
__global__ __launch_bounds__(256, 8) void ltc_accum(
    const float* __restrict__ inputs,   // NB x NI
    const float* __restrict__ state,    // NB x NH
    const float* __restrict__ smu, const float* __restrict__ ssg,
    const float* __restrict__ sW,  const float* __restrict__ ser,
    const float* __restrict__ imu, const float* __restrict__ isg,
    const float* __restrict__ iW,  const float* __restrict__ ier,
    float* __restrict__ wsNum, float* __restrict__ wsDen)
{
    __shared__ float xs[CHUNK][TB];   // x/state chunk, [row][batch]

    const int bi = blockIdx.x;
    // XCD-aware decode: XCD = bi & 7 (round-robin heuristic). Each XCD sees
    // sigma in {4x..4x+3} only -> 4 chunks x 256KB = 1MB params, L2-resident.
    const int x     = bi & 7;
    const int j     = bi >> 3;                  // 0..255
    const int sigma = x * 4 + (j & 3);          // 0..31
    const int btile = (j >> 2) & (NT - 1);      // 0..31
    const int hhalf = j >> 7;                   // 0..1
    const int b0 = btile * TB;
    const int h  = hhalf * HBLK + threadIdx.x;

    const bool sens = sigma < 16;
    const int  r0   = (sens ? sigma : sigma - 16) * CHUNK;

    // Side-selected pointers (block-uniform -> scalar select, no divergence).
    const float* __restrict__ src  = sens ? inputs : state;   // NB x 512
    const float* __restrict__ Pmu  = sens ? smu : imu;
    const float* __restrict__ Psg  = sens ? ssg : isg;
    const float* __restrict__ PW   = sens ? sW  : iW;
    const float* __restrict__ Per  = sens ? ser : ier;

    // Stage x/state chunk to LDS, [row][batch] layout. CHUNK*TB == 256.
    {
        const int ii = threadIdx.x >> 3, bb = threadIdx.x & (TB - 1);
        xs[ii][bb] = src[(b0 + bb) * 512 + r0 + ii];
    }
    __syncthreads();

    float num[TB], den[TB];
#pragma unroll
    for (int bb = 0; bb < TB; ++bb) { num[bb] = 0.f; den[bb] = 0.f; }

    const float LOG2E = 1.44269504088896340736f;
    const int base = r0 * NH + h;

    // Distance-2 rotating param prefetch (slots become registers under
    // unroll 2). Loads for iter ii+2 issue before iter ii's compute.
    float pmu[2], psg[2], pw[2], per_[2];
    pmu[0] = Pmu[base];      psg[0] = Psg[base];
    pw [0] = PW [base];      per_[0] = Per[base];
    pmu[1] = Pmu[base + NH]; psg[1] = Psg[base + NH];
    pw [1] = PW [base + NH]; per_[1] = Per[base + NH];

    // sigmoid((x-mu)*sig) = 1/(1+exp2(c - x*a)), a = sig*log2e, c = mu*a
#pragma unroll 2
    for (int ii = 0; ii < CHUNK; ++ii) {
        const int slot = ii & 1;
        const float mu = pmu[slot], sg = psg[slot];
        const float W  = pw[slot],  er = per_[slot];
        if (ii + 2 < CHUNK) {
            const int pn = base + (ii + 2) * NH;
            pmu[slot] = Pmu[pn]; psg[slot] = Psg[pn];
            pw [slot] = PW [pn]; per_[slot] = Per[pn];
        }
        const float a  = sg * LOG2E;
        const float c  = mu * a;
        const float We = W * er;
        float r[TB];                               // 8 independent chains
#pragma unroll
        for (int bb = 0; bb < TB; ++bb)
            r[bb] = fast_rcp(1.0f + fast_exp2(c - xs[ii][bb] * a));
#pragma unroll
        for (int bb = 0; bb < TB; ++bb) {
            den[bb] += W  * r[bb];
            num[bb] += We * r[bb];
        }
    }

#pragma unroll
    for (int bb = 0; bb < TB; ++bb) {
        unsafeAtomicAdd(&wsNum[(b0 + bb) * NH + h], num[bb]);  // global_atomic_add_f32
        unsafeAtomicAdd(&wsDen[(b0 + bb) * NH + h], den[bb]);
    }
}

// Epilogue: one thread per (b,h). Cheap relative to accumulation.
__global__ __launch_bounds__(256) void ltc_epilogue(
    const float* __restrict__ state,
    const float* __restrict__ vleak, const float* __restrict__ gleak,
    const float* __restrict__ cm,
    const float* __restrict__ wsNum, const float* __restrict__ wsDen,
    float* __restrict__ out)
{
    const int t = blockIdx.x * 256 + threadIdx.x;  // < NB*NH
    const int h = t & (NH - 1);
    const float st = state[t];
    const float gl = gleak[h];
    const float vl = vleak[h];
    const float c  = cm[h];
    const float wnum = wsNum[t];
    const float wden = wsDen[t];
    const float eps = 1e-8f;
    const float G = gl + wden;
    const float tau = c / (G + eps);
    const float numerator = c * st + gl * vl + wnum;
    const float denominator = c + G;
    const float v_inf = numerator / (denominator + eps);
    const float next = v_inf + (st - v_inf) * expf(-0.1f / (tau + eps));
    out[t] = tanhf(next);
}

extern "C" void kernel_launch(void* const* d_in, const int* in_sizes, int n_in,
                              void* d_out, int out_size, void* d_ws, size_t ws_size,
                              hipStream_t stream) {
    const float* inputs = (const float*)d_in[0];
    const float* state  = (const float*)d_in[1];
    const float* smu    = (const float*)d_in[2];
    const float* ssg    = (const float*)d_in[3];
    const float* sW     = (const float*)d_in[4];
    const float* ser    = (const float*)d_in[5];
    const float* imu    = (const float*)d_in[6];
    const float* isg    = (const float*)d_in[7];
    const float* iW     = (const float*)d_in[8];
    const float* ier    = (const float*)d_in[9];
    const float* vleak  = (const float*)d_in[10];
    const float* gleak  = (const float*)d_in[11];
    const float* cm     = (const float*)d_in[12];

    float* wsNum = (float*)d_ws;
    float* wsDen = wsNum + NB * NH;

    // ws is re-poisoned (0xAA) before every timed launch -> zero it ourselves.
    hipMemsetAsync(d_ws, 0, 2ull * NB * NH * sizeof(float), stream);

    ltc_accum<<<dim3(NSPL * NT * 2), dim3(256), 0, stream>>>(
        inputs, state, smu, ssg, sW, ser, imu, isg, iW, ier, wsNum, wsDen);
    ltc_epilogue<<<dim3(NB * NH / 256), dim3(256), 0, stream>>>(
        state, vleak, gleak, cm, wsNum, wsDen, (float*)d_out);
}

// Round 7
// 123.228 us; speedup vs baseline: 1.0473x; 1.0473x over previous
//
#include <hip/hip_runtime.h>
#include <stdint.h>

// Problem: LTCCell  B=256, I=512, H=512. ALL tensors float32, output float32.
// R5: 8 waves/SIMD didn't help (46.5us, VALUBusy 58%). R6: swizzle+prefetch
// regressed (51us). Model that fits all data: v_exp_f32/v_rcp_f32 are
// 1/8-rate (16 cyc/wave-op) -> per-eval 40 cyc, 24 counted as VALU issue ->
// predicts 34us+overhead and VALUBusy 60%, occupancy-independent. Trans pipe
// is the wall.
// R7: REMOVE all transcendentals. sigmoid(z) ~= 0.5 + zc*P5(zc^2),
// zc=clamp(z,+-7); P5 = degree-11 odd Newton/Chebyshev fit (max sigma err
// ~3.5e-3; output sensitivity (dnum+0.3*dden)/252 -> ~e-4 impact). The 0.5
// is factored: accumulate sum(W*g) and sum(W); add 0.5*sum(W) at the end.
// Per-eval: 12 full-rate VALU ops, zero trans.
constexpr int NB = 256;
constexpr int NI = 512;
constexpr int NH = 512;

constexpr int TB    = 8;    // batches register-blocked per lane
constexpr int NT    = 32;   // batch tiles: 256/8
constexpr int CHUNK = 32;   // reduction rows per block
constexpr int NSPL  = 32;   // splits: 16 sensory chunks + 16 inter chunks
constexpr int HBLK  = 256;  // h columns per block (== blockDim.x)

// Odd poly for sigmoid(z)-0.5 = z*P(z^2), fit on |z|<=7 (Newton interp at
// Chebyshev-s nodes; verified err ~+-3e-3 at z=1,3.5,5,6,7).
__device__ __constant__ const float SC0 =  0.24781886f;
__device__ __constant__ const float SC1 = -0.01739900f;
__device__ __constant__ const float SC2 =  9.68558e-4f;
__device__ __constant__ const float SC3 = -3.09967e-5f;
__device__ __constant__ const float SC4 =  5.03772e-7f;
__device__ __constant__ const float SC5 = -3.21180e-9f;

// Each block = (split sigma, batch tile, h half). 2048 blocks x 256 thr.
// Lane <-> h column, 8 batches register-blocked per lane. Partials combined
// via f32 atomics into the f32 workspace.
__global__ __launch_bounds__(256, 6) void ltc_accum(
    const float* __restrict__ inputs,   // NB x NI
    const float* __restrict__ state,    // NB x NH
    const float* __restrict__ smu, const float* __restrict__ ssg,
    const float* __restrict__ sW,  const float* __restrict__ ser,
    const float* __restrict__ imu, const float* __restrict__ isg,
    const float* __restrict__ iW,  const float* __restrict__ ier,
    float* __restrict__ wsNum, float* __restrict__ wsDen)
{
    __shared__ float xs[CHUNK][TB];   // x/state chunk, [row][batch]

    const int bi    = blockIdx.x;
    const int sigma = bi & (NSPL - 1);          // 32 splits
    const int btile = (bi >> 5) & (NT - 1);     // 32 batch tiles
    const int hhalf = bi >> 10;                 // 2 h halves
    const int b0 = btile * TB;
    const int h  = hhalf * HBLK + threadIdx.x;

    const bool sens = sigma < 16;
    const int  r0   = (sens ? sigma : sigma - 16) * CHUNK;

    // Side-selected pointers (block-uniform -> scalar select, no divergence).
    const float* __restrict__ src  = sens ? inputs : state;   // NB x 512
    const float* __restrict__ Pmu  = sens ? smu : imu;
    const float* __restrict__ Psg  = sens ? ssg : isg;
    const float* __restrict__ PW   = sens ? sW  : iW;
    const float* __restrict__ Per  = sens ? ser : ier;

    // Stage x/state chunk to LDS, [row][batch] layout. CHUNK*TB == 256.
    {
        const int ii = threadIdx.x >> 3, bb = threadIdx.x & (TB - 1);
        xs[ii][bb] = src[(b0 + bb) * 512 + r0 + ii];
    }
    __syncthreads();

    float numA[TB], denA[TB];                 // sums of We*g and W*g
#pragma unroll
    for (int bb = 0; bb < TB; ++bb) { numA[bb] = 0.f; denA[bb] = 0.f; }
    float sWsum = 0.f, sWesum = 0.f;          // sums of W and We (bb-indep)

    // sigma(z) ~= 0.5 + zc*P5(zc^2), zc = clamp(z, -7, 7), z = x*a - c
#pragma unroll 2
    for (int ii = 0; ii < CHUNK; ++ii) {
        const int p = (r0 + ii) * NH + h;          // coalesced across lanes
        const float a  = Psg[p];
        const float c  = Pmu[p] * a;
        const float W  = PW[p];
        const float We = W * Per[p];
        sWsum  += W;
        sWesum += We;
#pragma unroll
        for (int bb = 0; bb < TB; ++bb) {
            const float z  = __builtin_fmaf(xs[ii][bb], a, -c);
            const float zc = fminf(fmaxf(z, -7.0f), 7.0f);
            const float s  = zc * zc;
            float pl = __builtin_fmaf(SC5, s, SC4);
            pl = __builtin_fmaf(pl, s, SC3);
            pl = __builtin_fmaf(pl, s, SC2);
            pl = __builtin_fmaf(pl, s, SC1);
            pl = __builtin_fmaf(pl, s, SC0);
            const float g = zc * pl;               // sigma - 0.5
            denA[bb] = __builtin_fmaf(W,  g, denA[bb]);
            numA[bb] = __builtin_fmaf(We, g, numA[bb]);
        }
    }

#pragma unroll
    for (int bb = 0; bb < TB; ++bb) {
        const float den = __builtin_fmaf(0.5f, sWsum,  denA[bb]);
        const float num = __builtin_fmaf(0.5f, sWesum, numA[bb]);
        unsafeAtomicAdd(&wsNum[(b0 + bb) * NH + h], num);  // global_atomic_add_f32
        unsafeAtomicAdd(&wsDen[(b0 + bb) * NH + h], den);
    }
}

// Epilogue: one thread per (b,h). Exact math (off the hot path).
__global__ __launch_bounds__(256) void ltc_epilogue(
    const float* __restrict__ state,
    const float* __restrict__ vleak, const float* __restrict__ gleak,
    const float* __restrict__ cm,
    const float* __restrict__ wsNum, const float* __restrict__ wsDen,
    float* __restrict__ out)
{
    const int t = blockIdx.x * 256 + threadIdx.x;  // < NB*NH
    const int h = t & (NH - 1);
    const float st = state[t];
    const float gl = gleak[h];
    const float vl = vleak[h];
    const float c  = cm[h];
    const float wnum = wsNum[t];
    const float wden = wsDen[t];
    const float eps = 1e-8f;
    const float G = gl + wden;
    const float tau = c / (G + eps);
    const float numerator = c * st + gl * vl + wnum;
    const float denominator = c + G;
    const float v_inf = numerator / (denominator + eps);
    const float next = v_inf + (st - v_inf) * expf(-0.1f / (tau + eps));
    out[t] = tanhf(next);
}

extern "C" void kernel_launch(void* const* d_in, const int* in_sizes, int n_in,
                              void* d_out, int out_size, void* d_ws, size_t ws_size,
                              hipStream_t stream) {
    const float* inputs = (const float*)d_in[0];
    const float* state  = (const float*)d_in[1];
    const float* smu    = (const float*)d_in[2];
    const float* ssg    = (const float*)d_in[3];
    const float* sW     = (const float*)d_in[4];
    const float* ser    = (const float*)d_in[5];
    const float* imu    = (const float*)d_in[6];
    const float* isg    = (const float*)d_in[7];
    const float* iW     = (const float*)d_in[8];
    const float* ier    = (const float*)d_in[9];
    const float* vleak  = (const float*)d_in[10];
    const float* gleak  = (const float*)d_in[11];
    const float* cm     = (const float*)d_in[12];

    float* wsNum = (float*)d_ws;
    float* wsDen = wsNum + NB * NH;

    // ws is re-poisoned (0xAA) before every timed launch -> zero it ourselves.
    hipMemsetAsync(d_ws, 0, 2ull * NB * NH * sizeof(float), stream);

    ltc_accum<<<dim3(NSPL * NT * 2), dim3(256), 0, stream>>>(
        inputs, state, smu, ssg, sW, ser, imu, isg, iW, ier, wsNum, wsDen);
    ltc_epilogue<<<dim3(NB * NH / 256), dim3(256), 0, stream>>>(
        state, vleak, gleak, cm, wsNum, wsDen, (float*)d_out);
}